// Round 3
// baseline (66.333 us; speedup 1.0000x reference)
//
#include <hip/hip_runtime.h>
#include <hip/hip_bf16.h>

typedef float  f32x4 __attribute__((ext_vector_type(4)));
typedef short  s16x8 __attribute__((ext_vector_type(8)));
typedef __bf16 b16x8 __attribute__((ext_vector_type(8)));

#define NROWS 8192
#define NWAVES 4096   // 1024 blocks x 4 waves; 2 rows per wave, statically unrolled

__device__ __forceinline__ f32x4 mfma_bf16(s16x8 a, s16x8 b, f32x4 c) {
    return __builtin_amdgcn_mfma_f32_16x16x32_bf16(
        __builtin_bit_cast(b16x8, a), __builtin_bit_cast(b16x8, b), c, 0, 0, 0);
}

__device__ __forceinline__ short f2b(float f) {
    return __builtin_bit_cast(short, (__bf16)f);
}

__device__ __forceinline__ s16x8 pack8(f32x4 a, f32x4 b) {
    s16x8 r;
    r[0] = f2b(a[0]); r[1] = f2b(a[1]); r[2] = f2b(a[2]); r[3] = f2b(a[3]);
    r[4] = f2b(b[0]); r[5] = f2b(b[1]); r[6] = f2b(b[2]); r[7] = f2b(b[3]);
    return r;
}

// kappa k-map fragment loader: slot s<4 <- col cb + g*4 + s ; slot s>=4 <- col cb + 16 + g*4 + (s-4)
// Across the 4 g-lanes of a fixed c, each f32x4 load covers 64 contiguous bytes.
__device__ __forceinline__ s16x8 load_frag_k(const float* __restrict__ mat, int row, int cb, int g) {
    const float* p = mat + row * 64 + cb + g * 4;
    return pack8(*reinterpret_cast<const f32x4*>(p), *reinterpret_cast<const f32x4*>(p + 16));
}

// Per row n: Out = W1 (64x64) * X (64x64) * W2^T (64x64), all MFMA k-maps use kappa.
// Stage 1: T = X @ W2^T.  acc1[mt][nt]: lane(c,g) holds T[mt*16+g*4+r][nt*16+c].
// Register transpose: a2[jt][kh] = pack8(acc1[2kh][jt], acc1[2kh+1][jt]) is EXACTLY
//   the A-fragment of T^T (row=jt*16+c, k-slots via the same kappa map).
// Stage 2: Out^T = T^T @ W1^T with B = W1 rows under kappa.
//   acc2: lane(c,g) holds Out[it*16+c][jt*16+g*4+r] -> f32x4 nontemporal store.
__global__ __launch_bounds__(256, 2) void kron2_kernel(
    const float* __restrict__ data, const float* __restrict__ W1,
    const float* __restrict__ W2, float* __restrict__ out)
{
    const int lane = threadIdx.x & 63;
    const int c    = lane & 15;
    const int g    = lane >> 4;

    // Persistent weight fragments (both under the kappa k-map).
    // Stage-1 B: lane holds W2^T[kappa][col=c'] = W2[t*16+c][kappa]
    // Stage-2 B: lane holds W1^T[kappa][col=c'] = W1[t*16+c][kappa]
    s16x8 w2f[4][2], w1f[4][2];
    #pragma unroll
    for (int t = 0; t < 4; ++t)
      #pragma unroll
      for (int kh = 0; kh < 2; ++kh) {
        w2f[t][kh] = load_frag_k(W2, t * 16 + c, kh * 32, g);
        w1f[t][kh] = load_frag_k(W1, t * 16 + c, kh * 32, g);
      }

    const int wgid = (int)((blockIdx.x * blockDim.x + threadIdx.x) >> 6);

    #pragma unroll
    for (int rr = 0; rr < NROWS / NWAVES; ++rr) {
        const int n = wgid + rr * NWAVES;
        const float* X = data + (size_t)n * 4096;

        // ---- stage 1: T = X @ W2^T (A = X under kappa, direct from global) ----
        s16x8 xa[4][2];
        #pragma unroll
        for (int mt = 0; mt < 4; ++mt) {
            xa[mt][0] = load_frag_k(X, mt * 16 + c, 0,  g);
            xa[mt][1] = load_frag_k(X, mt * 16 + c, 32, g);
        }
        f32x4 acc1[4][4];
        #pragma unroll
        for (int mt = 0; mt < 4; ++mt)
          #pragma unroll
          for (int nt = 0; nt < 4; ++nt) {
            f32x4 a = {0.f, 0.f, 0.f, 0.f};
            a = mfma_bf16(xa[mt][0], w2f[nt][0], a);
            a = mfma_bf16(xa[mt][1], w2f[nt][1], a);
            acc1[mt][nt] = a;
          }

        // ---- register transpose: A-fragments of T^T via kappa ----
        s16x8 a2[4][2];
        #pragma unroll
        for (int jt = 0; jt < 4; ++jt) {
            a2[jt][0] = pack8(acc1[0][jt], acc1[1][jt]);
            a2[jt][1] = pack8(acc1[2][jt], acc1[3][jt]);
        }

        // ---- stage 2: Out^T = T^T @ W1^T ; nontemporal f32x4 stores ----
        #pragma unroll
        for (int it = 0; it < 4; ++it) {
            float* O = out + (size_t)n * 4096 + (it * 16 + c) * 64;
            #pragma unroll
            for (int jt = 0; jt < 4; ++jt) {
                f32x4 a = {0.f, 0.f, 0.f, 0.f};
                a = mfma_bf16(a2[jt][0], w1f[it][0], a);
                a = mfma_bf16(a2[jt][1], w1f[it][1], a);
                __builtin_nontemporal_store(a,
                    reinterpret_cast<f32x4*>(O + jt * 16 + g * 4));
            }
        }
    }
}

extern "C" void kernel_launch(void* const* d_in, const int* in_sizes, int n_in,
                              void* d_out, int out_size, void* d_ws, size_t ws_size,
                              hipStream_t stream) {
    const float* data = (const float*)d_in[0];
    const float* W1   = (const float*)d_in[1];
    const float* W2   = (const float*)d_in[2];
    float* out        = (float*)d_out;
    dim3 grid(NWAVES / 4), block(256);
    hipLaunchKernelGGL(kron2_kernel, grid, block, 0, stream, data, W1, W2, out);
}